// Round 4
// baseline (138.021 us; speedup 1.0000x reference)
//
#include <hip/hip_runtime.h>
#include <stdint.h>

#define B_N   1024
#define D_DIM 512
#define H_DIM 512
#define A_DIM 18
#define T_N   64
#define HTILE 256
#define SMAX  32   // sample slots per block pass

// ---------------- K1: detect task_id dtype, bucket samples by task ----------------
__global__ __launch_bounds__(1024) void bucket_kernel(const int* __restrict__ raw,
                                                      int* __restrict__ counts,
                                                      int* __restrict__ offsets,
                                                      int* __restrict__ order,
                                                      int* __restrict__ tid32) {
    __shared__ int cnt[T_N];
    __shared__ int off[T_N];
    __shared__ int odd_nonzero;
    int t = threadIdx.x;
    if (t == 0) odd_nonzero = 0;
    if (t < T_N) cnt[t] = 0;
    __syncthreads();
    int probe = raw[t];                           // first 4 KB, valid for both dtypes
    if ((t & 1) && probe != 0) odd_nonzero = 1;   // benign race: all writers store 1
    __syncthreads();
    int task = odd_nonzero ? raw[t]               // int32 layout
                           : raw[2 * t];          // int64 layout: low word of element t
    tid32[t] = task;
    int pos = atomicAdd(&cnt[task], 1);
    __syncthreads();
    if (t == 0) {
        int acc = 0;
        for (int k = 0; k < T_N; ++k) { off[k] = acc; acc += cnt[k]; }
    }
    __syncthreads();
    order[off[task] + pos] = t;
    if (t < T_N) { counts[t] = cnt[t]; offsets[t] = off[t]; }
}

// ---------------- K2: fc1 partial GEMM, grid (task, htile, ksplit) ----------------
template <int KSP>
__global__ __launch_bounds__(256) void fc1_kernel(const float* __restrict__ xs,
                                                  const float* __restrict__ w1,
                                                  const int* __restrict__ counts,
                                                  const int* __restrict__ offsets,
                                                  const int* __restrict__ order,
                                                  float* __restrict__ hpre) {
    constexpr int DK = D_DIM / KSP;
    int task  = blockIdx.x;
    int htile = blockIdx.y;
    int ksp   = blockIdx.z;
    int n = counts[task];
    if (n == 0) return;
    int off  = offsets[task];
    int lane = threadIdx.x & 63;
    int wv4  = threadIdx.x >> 6;         // wave id 0..3
    int hbase = htile * HTILE + lane * 4;
    int d0    = ksp * DK;
    const float* wbase = w1 + ((size_t)task * D_DIM + d0) * H_DIM + hbase;
    float* hout = hpre + (size_t)ksp * ((size_t)B_N * H_DIM);

    __shared__ __align__(16) float xlds[SMAX * DK];

    for (int sb = 0; sb < n; sb += SMAX) {
        int ns = min(SMAX, n - sb);
        // stage xs rows (coalesced)
        for (int idx = threadIdx.x; idx < ns * DK; idx += 256) {
            int sl = idx / DK;
            int dl = idx - sl * DK;
            int smp = order[off + sb + sl];
            xlds[idx] = xs[(size_t)smp * D_DIM + d0 + dl];
        }
        __syncthreads();

        float4 acc[8];
#pragma unroll
        for (int j = 0; j < 8; ++j) acc[j] = make_float4(0.f, 0.f, 0.f, 0.f);

        for (int d = 0; d < DK; d += 8) {
            float4 wvr[8];
#pragma unroll
            for (int u = 0; u < 8; ++u)
                wvr[u] = *(const float4*)(wbase + (size_t)(d + u) * H_DIM);
#pragma unroll
            for (int j = 0; j < 8; ++j) {
                int sl = wv4 + 4 * j;
                if (sl < ns) {
                    const float* xp = &xlds[sl * DK + d];
                    float4 xa = *(const float4*)xp;
                    float4 xb = *(const float4*)(xp + 4);
                    float xv[8] = {xa.x, xa.y, xa.z, xa.w, xb.x, xb.y, xb.z, xb.w};
#pragma unroll
                    for (int u = 0; u < 8; ++u) {
                        acc[j].x = fmaf(xv[u], wvr[u].x, acc[j].x);
                        acc[j].y = fmaf(xv[u], wvr[u].y, acc[j].y);
                        acc[j].z = fmaf(xv[u], wvr[u].z, acc[j].z);
                        acc[j].w = fmaf(xv[u], wvr[u].w, acc[j].w);
                    }
                }
            }
        }

#pragma unroll
        for (int j = 0; j < 8; ++j) {
            int sl = wv4 + 4 * j;
            if (sl < ns) {
                int smp = order[off + sb + sl];
                *(float4*)(hout + (size_t)smp * H_DIM + hbase) = acc[j];
            }
        }
        __syncthreads();
    }
}

// ---------------- threefry2x32, partitionable counter mode, key = (0, 1) --------
// Modern JAX (jax_threefry_partitionable=True, the default): element i is
// encrypted independently with counter (x0, x1) = (i >> 32, i & 0xffffffff);
// 32-bit output folds the two cipher words: bits = y0 ^ y1.
__device__ __forceinline__ uint32_t rotl32(uint32_t x, int r) {
    return (x << r) | (x >> (32 - r));
}

__device__ __forceinline__ uint32_t threefry_bits_part(uint32_t i) {
    uint32_t x0 = 0u;        // i >> 32 for i < 2^32
    uint32_t x1 = i;
    const uint32_t ks0 = 0u, ks1 = 1u, ks2 = 0x1BD11BDAu ^ 0u ^ 1u;
    x0 += ks0; x1 += ks1;
#define TFR(r) { x0 += x1; x1 = rotl32(x1, (r)); x1 ^= x0; }
    TFR(13) TFR(15) TFR(26) TFR(6)
    x0 += ks1; x1 += ks2 + 1u;
    TFR(17) TFR(29) TFR(16) TFR(24)
    x0 += ks2; x1 += ks0 + 2u;
    TFR(13) TFR(15) TFR(26) TFR(6)
    x0 += ks0; x1 += ks1 + 3u;
    TFR(17) TFR(29) TFR(16) TFR(24)
    x0 += ks1; x1 += ks2 + 4u;
    TFR(13) TFR(15) TFR(26) TFR(6)
    x0 += ks2; x1 += ks0 + 5u;
#undef TFR
    return x0 ^ x1;
}

// ---------------- K3: relu + fc2 + log_softmax + gumbel sample, one wave/sample ----------------
template <int KSP>
__global__ __launch_bounds__(64) void head_kernel(const int* __restrict__ tid32,
                                                  const float* __restrict__ hpre,
                                                  const float* __restrict__ b1,
                                                  const float* __restrict__ w2,
                                                  const float* __restrict__ b2,
                                                  float* __restrict__ out) {
    int s = blockIdx.x;
    int lane = threadIdx.x;
    int t = tid32[s];

    // h = relu(sum_k partial_k + b1)
    float hreg[H_DIM / 64];
#pragma unroll
    for (int k = 0; k < H_DIM / 64; ++k) {
        int h = lane + 64 * k;
        size_t p = (size_t)s * H_DIM + h;
        float v = b1[(size_t)t * H_DIM + h];
#pragma unroll
        for (int q = 0; q < KSP; ++q)
            v += hpre[(size_t)q * ((size_t)B_N * H_DIM) + p];
        hreg[k] = fmaxf(v, 0.f);
    }

    // partial logits (per-lane over its strided h)
    float la[A_DIM];
#pragma unroll
    for (int a = 0; a < A_DIM; ++a) la[a] = 0.f;
#pragma unroll
    for (int k = 0; k < H_DIM / 64; ++k) {
        int h = lane + 64 * k;
        const float2* w2r = (const float2*)(w2 + ((size_t)t * H_DIM + h) * A_DIM);
        float hk = hreg[k];
#pragma unroll
        for (int a2 = 0; a2 < A_DIM / 2; ++a2) {
            float2 ww = w2r[a2];
            la[2 * a2]     = fmaf(hk, ww.x, la[2 * a2]);
            la[2 * a2 + 1] = fmaf(hk, ww.y, la[2 * a2 + 1]);
        }
    }

    // reduce partial logits across the wave via LDS
    __shared__ float red[64 * A_DIM];
    __shared__ float logits_lds[A_DIM];
#pragma unroll
    for (int a = 0; a < A_DIM; ++a) red[lane * A_DIM + a] = la[a];
    __syncthreads();
    if (lane < A_DIM) {
        float sum = b2[(size_t)t * A_DIM + lane];
        for (int l = 0; l < 64; ++l) sum += red[l * A_DIM + lane];
        logits_lds[lane] = sum;
    }
    __syncthreads();

    float lg = (lane < A_DIM) ? logits_lds[lane] : -INFINITY;

    // gumbel + argmax (first-index tie-break, matching jnp.argmax)
    float z = -INFINITY;
    if (lane < A_DIM) {
        uint32_t bits = threefry_bits_part((uint32_t)(s * A_DIM + lane));
        float f = __uint_as_float(0x3f800000u | (bits >> 9)) - 1.0f;
        float u = fmaxf(f, 1.17549435e-38f);   // jnp.finfo(f32).tiny
        float g = -logf(-logf(u));
        z = lg + g;
    }
    int idx = lane;
#pragma unroll
    for (int o = 1; o < 64; o <<= 1) {
        float oz = __shfl_xor(z, o);
        int   oi = __shfl_xor(idx, o);
        if (oz > z || (oz == z && oi < idx)) { z = oz; idx = oi; }
    }

    // log-softmax pieces
    float mx = lg;
#pragma unroll
    for (int o = 1; o < 64; o <<= 1) mx = fmaxf(mx, __shfl_xor(mx, o));
    float e = (lane < A_DIM) ? expf(lg - mx) : 0.f;
#pragma unroll
    for (int o = 1; o < 64; o <<= 1) e += __shfl_xor(e, o);
    float lse = mx + logf(e);
    float lp = lg - lse;
    float c = (lane < A_DIM) ? expf(lp) * lp : 0.f;
#pragma unroll
    for (int o = 1; o < 64; o <<= 1) c += __shfl_xor(c, o);

    if (lane == 0) {
        out[s]             = (float)idx;            // action
        out[B_N + s]       = logits_lds[idx] - lse; // log_prob
        out[2 * B_N + s]   = -c;                    // entropy
    }
}

extern "C" void kernel_launch(void* const* d_in, const int* in_sizes, int n_in,
                              void* d_out, int out_size, void* d_ws, size_t ws_size,
                              hipStream_t stream) {
    const float* xs      = (const float*)d_in[0];
    const int*   traw    = (const int*)d_in[1];   // int32 or int64 — detected on device
    const float* w1      = (const float*)d_in[2];
    const float* b1      = (const float*)d_in[3];
    const float* w2      = (const float*)d_in[4];
    const float* b2      = (const float*)d_in[5];
    float* out = (float*)d_out;                   // float32 (proven by round-3 21.25 signature)
    char*  ws  = (char*)d_ws;

    const size_t part_bytes = (size_t)B_N * H_DIM * sizeof(float);  // 2 MB per K-split partial
    const size_t int_bytes  = (64 + 64 + B_N + B_N) * sizeof(int);

    // Pick K-split by available workspace (constant per process -> graph-safe).
    int ksp = 4;
    if (ws_size < 4 * part_bytes + int_bytes) ksp = 2;
    if (ws_size < 2 * part_bytes + int_bytes) ksp = 1;

    float* hpre   = (float*)ws;
    int*   ints   = (int*)(ws + (size_t)ksp * part_bytes);
    int* counts   = ints;
    int* offsets  = ints + 64;
    int* order    = ints + 128;
    int* tid32    = ints + 128 + B_N;

    bucket_kernel<<<1, 1024, 0, stream>>>(traw, counts, offsets, order, tid32);
    if (ksp == 4) {
        fc1_kernel<4><<<dim3(T_N, 2, 4), 256, 0, stream>>>(xs, w1, counts, offsets, order, hpre);
        head_kernel<4><<<B_N, 64, 0, stream>>>(tid32, hpre, b1, w2, b2, out);
    } else if (ksp == 2) {
        fc1_kernel<2><<<dim3(T_N, 2, 2), 256, 0, stream>>>(xs, w1, counts, offsets, order, hpre);
        head_kernel<2><<<B_N, 64, 0, stream>>>(tid32, hpre, b1, w2, b2, out);
    } else {
        fc1_kernel<1><<<dim3(T_N, 2, 1), 256, 0, stream>>>(xs, w1, counts, offsets, order, hpre);
        head_kernel<1><<<B_N, 64, 0, stream>>>(tid32, hpre, b1, w2, b2, out);
    }
}

// Round 5
// 135.578 us; speedup vs baseline: 1.0180x; 1.0180x over previous
//
#include <hip/hip_runtime.h>
#include <stdint.h>

#define B_N   1024
#define D_DIM 512
#define H_DIM 512
#define A_DIM 18
#define T_N   64
#define HTILE 256
#define SMAX  32   // sample slots per block pass

// ---------------- K1: detect task_id dtype, bucket samples by task ----------------
__global__ __launch_bounds__(1024) void bucket_kernel(const int* __restrict__ raw,
                                                      int* __restrict__ counts,
                                                      int* __restrict__ offsets,
                                                      int* __restrict__ order,
                                                      int* __restrict__ tid32) {
    __shared__ int cnt[T_N];
    __shared__ int off[T_N];
    __shared__ int odd_nonzero;
    int t = threadIdx.x;
    if (t == 0) odd_nonzero = 0;
    if (t < T_N) cnt[t] = 0;
    __syncthreads();
    int probe = raw[t];                           // first 4 KB, valid for both dtypes
    if ((t & 1) && probe != 0) odd_nonzero = 1;   // benign race: all writers store 1
    __syncthreads();
    int task = odd_nonzero ? raw[t]               // int32 layout
                           : raw[2 * t];          // int64 layout: low word of element t
    tid32[t] = task;
    int pos = atomicAdd(&cnt[task], 1);
    __syncthreads();
    if (t == 0) {
        int acc = 0;
        for (int k = 0; k < T_N; ++k) { off[k] = acc; acc += cnt[k]; }
    }
    __syncthreads();
    order[off[task] + pos] = t;
    if (t < T_N) { counts[t] = cnt[t]; offsets[t] = off[t]; }
}

// ---------------- K2: fc1 partial GEMM, grid (task, htile, ksplit) ----------------
// (unchanged from the passing round-4 kernel)
template <int KSP>
__global__ __launch_bounds__(256) void fc1_kernel(const float* __restrict__ xs,
                                                  const float* __restrict__ w1,
                                                  const int* __restrict__ counts,
                                                  const int* __restrict__ offsets,
                                                  const int* __restrict__ order,
                                                  float* __restrict__ hpre) {
    constexpr int DK = D_DIM / KSP;
    int task  = blockIdx.x;
    int htile = blockIdx.y;
    int ksp   = blockIdx.z;
    int n = counts[task];
    if (n == 0) return;
    int off  = offsets[task];
    int lane = threadIdx.x & 63;
    int wv4  = threadIdx.x >> 6;         // wave id 0..3
    int hbase = htile * HTILE + lane * 4;
    int d0    = ksp * DK;
    const float* wbase = w1 + ((size_t)task * D_DIM + d0) * H_DIM + hbase;
    float* hout = hpre + (size_t)ksp * ((size_t)B_N * H_DIM);

    __shared__ __align__(16) float xlds[SMAX * DK];

    for (int sb = 0; sb < n; sb += SMAX) {
        int ns = min(SMAX, n - sb);
        // stage xs rows (coalesced)
        for (int idx = threadIdx.x; idx < ns * DK; idx += 256) {
            int sl = idx / DK;
            int dl = idx - sl * DK;
            int smp = order[off + sb + sl];
            xlds[idx] = xs[(size_t)smp * D_DIM + d0 + dl];
        }
        __syncthreads();

        float4 acc[8];
#pragma unroll
        for (int j = 0; j < 8; ++j) acc[j] = make_float4(0.f, 0.f, 0.f, 0.f);

        for (int d = 0; d < DK; d += 8) {
            float4 wvr[8];
#pragma unroll
            for (int u = 0; u < 8; ++u)
                wvr[u] = *(const float4*)(wbase + (size_t)(d + u) * H_DIM);
#pragma unroll
            for (int j = 0; j < 8; ++j) {
                int sl = wv4 + 4 * j;
                if (sl < ns) {                    // wave-uniform predicate (wv4 per-wave)
                    const float* xp = &xlds[sl * DK + d];
                    float4 xa = *(const float4*)xp;
                    float4 xb = *(const float4*)(xp + 4);
                    float xv[8] = {xa.x, xa.y, xa.z, xa.w, xb.x, xb.y, xb.z, xb.w};
#pragma unroll
                    for (int u = 0; u < 8; ++u) {
                        acc[j].x = fmaf(xv[u], wvr[u].x, acc[j].x);
                        acc[j].y = fmaf(xv[u], wvr[u].y, acc[j].y);
                        acc[j].z = fmaf(xv[u], wvr[u].z, acc[j].z);
                        acc[j].w = fmaf(xv[u], wvr[u].w, acc[j].w);
                    }
                }
            }
        }

#pragma unroll
        for (int j = 0; j < 8; ++j) {
            int sl = wv4 + 4 * j;
            if (sl < ns) {
                int smp = order[off + sb + sl];
                *(float4*)(hout + (size_t)smp * H_DIM + hbase) = acc[j];
            }
        }
        __syncthreads();
    }
}

// ---------------- threefry2x32, partitionable counter mode, key = (0, 1) --------
// (validated bit-exact in round 4 — do not touch)
__device__ __forceinline__ uint32_t rotl32(uint32_t x, int r) {
    return (x << r) | (x >> (32 - r));
}

__device__ __forceinline__ uint32_t threefry_bits_part(uint32_t i) {
    uint32_t x0 = 0u;        // i >> 32 for i < 2^32
    uint32_t x1 = i;
    const uint32_t ks0 = 0u, ks1 = 1u, ks2 = 0x1BD11BDAu ^ 0u ^ 1u;
    x0 += ks0; x1 += ks1;
#define TFR(r) { x0 += x1; x1 = rotl32(x1, (r)); x1 ^= x0; }
    TFR(13) TFR(15) TFR(26) TFR(6)
    x0 += ks1; x1 += ks2 + 1u;
    TFR(17) TFR(29) TFR(16) TFR(24)
    x0 += ks2; x1 += ks0 + 2u;
    TFR(13) TFR(15) TFR(26) TFR(6)
    x0 += ks0; x1 += ks1 + 3u;
    TFR(17) TFR(29) TFR(16) TFR(24)
    x0 += ks1; x1 += ks2 + 4u;
    TFR(13) TFR(15) TFR(26) TFR(6)
    x0 += ks2; x1 += ks0 + 5u;
#undef TFR
    return x0 ^ x1;
}

// ---------------- K3: relu + fc2 + log_softmax + gumbel sample, one wave/sample ----
// Rewritten: w2[t] staged into LDS via coalesced float4 (was: 72 divergent
// global loads/wave at 72 B lane stride); serial 64-row reduction replaced by
// 2-step shfl_xor pre-reduce + 16-row LDS sum. LDS 38.1 KB -> 4 blocks/CU,
// all 1024 blocks co-resident.
template <int KSP>
__global__ __launch_bounds__(64) void head_kernel(const int* __restrict__ tid32,
                                                  const float* __restrict__ hpre,
                                                  const float* __restrict__ b1,
                                                  const float* __restrict__ w2,
                                                  const float* __restrict__ b2,
                                                  float* __restrict__ out) {
    __shared__ __align__(16) float w2l[H_DIM * A_DIM];   // 9216 floats = 36 KB
    __shared__ float red[16][A_DIM];
    __shared__ float logits_lds[A_DIM];

    int s = blockIdx.x;
    int lane = threadIdx.x;
    int t = tid32[s];

    // ---- stage w2[t] into LDS, coalesced: 9216 floats = 36 float4 per lane ----
    const float4* g4 = (const float4*)(w2 + (size_t)t * (H_DIM * A_DIM));
    float4* l4 = (float4*)w2l;
#pragma unroll
    for (int i = 0; i < (H_DIM * A_DIM) / (64 * 4); ++i)   // 36 iters
        l4[i * 64 + lane] = g4[i * 64 + lane];

    // ---- h = relu(sum_k partial_k + b1) (overlaps with staging latency) ----
    float hreg[H_DIM / 64];
#pragma unroll
    for (int k = 0; k < H_DIM / 64; ++k) {
        int h = lane + 64 * k;
        size_t p = (size_t)s * H_DIM + h;
        float v = b1[(size_t)t * H_DIM + h];
#pragma unroll
        for (int q = 0; q < KSP; ++q)
            v += hpre[(size_t)q * ((size_t)B_N * H_DIM) + p];
        hreg[k] = fmaxf(v, 0.f);
    }
    __syncthreads();   // w2l visible (single wave: cheap)

    // ---- per-lane partial logits from LDS ----
    float la[A_DIM];
#pragma unroll
    for (int a = 0; a < A_DIM; ++a) la[a] = 0.f;
#pragma unroll
    for (int k = 0; k < H_DIM / 64; ++k) {
        int h = lane + 64 * k;
        const float2* row = (const float2*)&w2l[h * A_DIM];   // 72 B rows: 8 B aligned
        float hk = hreg[k];
#pragma unroll
        for (int a2 = 0; a2 < A_DIM / 2; ++a2) {
            float2 ww = row[a2];
            la[2 * a2]     = fmaf(hk, ww.x, la[2 * a2]);
            la[2 * a2 + 1] = fmaf(hk, ww.y, la[2 * a2 + 1]);
        }
    }

    // ---- reduce 64 partials: shfl_xor(1,2) -> 16 rows -> LDS -> 18-lane sum ----
#pragma unroll
    for (int a = 0; a < A_DIM; ++a) {
        la[a] += __shfl_xor(la[a], 1);
        la[a] += __shfl_xor(la[a], 2);
    }
    if ((lane & 3) == 0) {
        int g = lane >> 2;
#pragma unroll
        for (int a = 0; a < A_DIM; ++a) red[g][a] = la[a];
    }
    __syncthreads();
    if (lane < A_DIM) {
        float sum = b2[(size_t)t * A_DIM + lane];
#pragma unroll
        for (int g = 0; g < 16; ++g) sum += red[g][lane];
        logits_lds[lane] = sum;
    }
    __syncthreads();

    // ---- tail: identical to the validated round-4 code ----
    float lg = (lane < A_DIM) ? logits_lds[lane] : -INFINITY;

    float z = -INFINITY;
    if (lane < A_DIM) {
        uint32_t bits = threefry_bits_part((uint32_t)(s * A_DIM + lane));
        float f = __uint_as_float(0x3f800000u | (bits >> 9)) - 1.0f;
        float u = fmaxf(f, 1.17549435e-38f);   // jnp.finfo(f32).tiny
        float g = -logf(-logf(u));
        z = lg + g;
    }
    int idx = lane;
#pragma unroll
    for (int o = 1; o < 64; o <<= 1) {
        float oz = __shfl_xor(z, o);
        int   oi = __shfl_xor(idx, o);
        if (oz > z || (oz == z && oi < idx)) { z = oz; idx = oi; }
    }

    float mx = lg;
#pragma unroll
    for (int o = 1; o < 64; o <<= 1) mx = fmaxf(mx, __shfl_xor(mx, o));
    float e = (lane < A_DIM) ? expf(lg - mx) : 0.f;
#pragma unroll
    for (int o = 1; o < 64; o <<= 1) e += __shfl_xor(e, o);
    float lse = mx + logf(e);
    float lp = lg - lse;
    float c = (lane < A_DIM) ? expf(lp) * lp : 0.f;
#pragma unroll
    for (int o = 1; o < 64; o <<= 1) c += __shfl_xor(c, o);

    if (lane == 0) {
        out[s]             = (float)idx;            // action
        out[B_N + s]       = logits_lds[idx] - lse; // log_prob
        out[2 * B_N + s]   = -c;                    // entropy
    }
}

extern "C" void kernel_launch(void* const* d_in, const int* in_sizes, int n_in,
                              void* d_out, int out_size, void* d_ws, size_t ws_size,
                              hipStream_t stream) {
    const float* xs      = (const float*)d_in[0];
    const int*   traw    = (const int*)d_in[1];   // int32 or int64 — detected on device
    const float* w1      = (const float*)d_in[2];
    const float* b1      = (const float*)d_in[3];
    const float* w2      = (const float*)d_in[4];
    const float* b2      = (const float*)d_in[5];
    float* out = (float*)d_out;
    char*  ws  = (char*)d_ws;

    const size_t part_bytes = (size_t)B_N * H_DIM * sizeof(float);  // 2 MB per K-split partial
    const size_t int_bytes  = (64 + 64 + B_N + B_N) * sizeof(int);

    // Pick K-split by available workspace (constant per process -> graph-safe).
    int ksp = 4;
    if (ws_size < 4 * part_bytes + int_bytes) ksp = 2;
    if (ws_size < 2 * part_bytes + int_bytes) ksp = 1;

    float* hpre   = (float*)ws;
    int*   ints   = (int*)(ws + (size_t)ksp * part_bytes);
    int* counts   = ints;
    int* offsets  = ints + 64;
    int* order    = ints + 128;
    int* tid32    = ints + 128 + B_N;

    bucket_kernel<<<1, 1024, 0, stream>>>(traw, counts, offsets, order, tid32);
    if (ksp == 4) {
        fc1_kernel<4><<<dim3(T_N, 2, 4), 256, 0, stream>>>(xs, w1, counts, offsets, order, hpre);
        head_kernel<4><<<B_N, 64, 0, stream>>>(tid32, hpre, b1, w2, b2, out);
    } else if (ksp == 2) {
        fc1_kernel<2><<<dim3(T_N, 2, 2), 256, 0, stream>>>(xs, w1, counts, offsets, order, hpre);
        head_kernel<2><<<B_N, 64, 0, stream>>>(tid32, hpre, b1, w2, b2, out);
    } else {
        fc1_kernel<1><<<dim3(T_N, 2, 1), 256, 0, stream>>>(xs, w1, counts, offsets, order, hpre);
        head_kernel<1><<<B_N, 64, 0, stream>>>(tid32, hpre, b1, w2, b2, out);
    }
}

// Round 6
// 132.862 us; speedup vs baseline: 1.0388x; 1.0204x over previous
//
#include <hip/hip_runtime.h>
#include <stdint.h>

#define B_N   1024
#define D_DIM 512
#define H_DIM 512
#define A_DIM 18
#define T_N   64
#define HTILE 256
#define SMAX  32   // sample slots per block pass

// Inline task_id dtype detection (int32 vs int64), executed by one full wave.
// Lanes read the first 64 int32 words (valid under both layouts). For int64
// data the odd words are zero high-words of values 0..63; for int32 data they
// are 32 random task ids (all-zero probability 64^-32 ~ 1e-58).
__device__ __forceinline__ bool taskid_is_int32(const int* raw, int lane) {
    int probe = raw[lane];
    unsigned long long odd = __ballot((lane & 1) && probe != 0);
    return odd != 0ull;
}

// ---------------- K2: fc1 partial GEMM, grid (task, htile, ksplit) ----------------
// Self-bucketing: wave 0 scans the 1024 task ids (4 KB, L2-resident) and
// ballot-compacts the indices of samples belonging to blockIdx.x into LDS.
// Slot order is irrelevant: each sample's FMA chain is slot-independent.
template <int KSP>
__global__ __launch_bounds__(256) void fc1_kernel(const float* __restrict__ xs,
                                                  const float* __restrict__ w1,
                                                  const int* __restrict__ raw,
                                                  float* __restrict__ hpre) {
    constexpr int DK = D_DIM / KSP;
    int task  = blockIdx.x;
    int htile = blockIdx.y;
    int ksp   = blockIdx.z;
    int lane = threadIdx.x & 63;
    int wv4  = threadIdx.x >> 6;         // wave id 0..3

    __shared__ int slist[B_N];           // worst case: all samples one task
    __shared__ int s_n;
    __shared__ __align__(16) float xlds[SMAX * DK];

    if (threadIdx.x < 64) {
        bool is32 = taskid_is_int32(raw, lane);
        int base = 0;
        for (int c = 0; c < B_N; c += 64) {
            int id = is32 ? raw[c + lane] : raw[2 * (c + lane)];
            unsigned long long m = __ballot(id == task);
            if (id == task) {
                unsigned long long below = m & ((1ull << lane) - 1ull);
                slist[base + __popcll(below)] = c + lane;
            }
            base += __popcll(m);
        }
        if (lane == 0) s_n = base;
    }
    __syncthreads();
    int n = s_n;
    if (n == 0) return;

    int hbase = htile * HTILE + lane * 4;
    int d0    = ksp * DK;
    const float* wbase = w1 + ((size_t)task * D_DIM + d0) * H_DIM + hbase;
    float* hout = hpre + (size_t)ksp * ((size_t)B_N * H_DIM);

    for (int sb = 0; sb < n; sb += SMAX) {
        int ns = min(SMAX, n - sb);
        // stage xs rows (coalesced)
        for (int idx = threadIdx.x; idx < ns * DK; idx += 256) {
            int sl = idx / DK;
            int dl = idx - sl * DK;
            int smp = slist[sb + sl];
            xlds[idx] = xs[(size_t)smp * D_DIM + d0 + dl];
        }
        __syncthreads();

        float4 acc[8];
#pragma unroll
        for (int j = 0; j < 8; ++j) acc[j] = make_float4(0.f, 0.f, 0.f, 0.f);

        for (int d = 0; d < DK; d += 8) {
            float4 wvr[8];
#pragma unroll
            for (int u = 0; u < 8; ++u)
                wvr[u] = *(const float4*)(wbase + (size_t)(d + u) * H_DIM);
#pragma unroll
            for (int j = 0; j < 8; ++j) {
                int sl = wv4 + 4 * j;
                if (sl < ns) {                    // wave-uniform predicate (wv4 per-wave)
                    const float* xp = &xlds[sl * DK + d];
                    float4 xa = *(const float4*)xp;
                    float4 xb = *(const float4*)(xp + 4);
                    float xv[8] = {xa.x, xa.y, xa.z, xa.w, xb.x, xb.y, xb.z, xb.w};
#pragma unroll
                    for (int u = 0; u < 8; ++u) {
                        acc[j].x = fmaf(xv[u], wvr[u].x, acc[j].x);
                        acc[j].y = fmaf(xv[u], wvr[u].y, acc[j].y);
                        acc[j].z = fmaf(xv[u], wvr[u].z, acc[j].z);
                        acc[j].w = fmaf(xv[u], wvr[u].w, acc[j].w);
                    }
                }
            }
        }

#pragma unroll
        for (int j = 0; j < 8; ++j) {
            int sl = wv4 + 4 * j;
            if (sl < ns) {
                int smp = slist[sb + sl];
                *(float4*)(hout + (size_t)smp * H_DIM + hbase) = acc[j];
            }
        }
        __syncthreads();
    }
}

// ---------------- threefry2x32, partitionable counter mode, key = (0, 1) --------
// (validated bit-exact in round 4 — do not touch)
__device__ __forceinline__ uint32_t rotl32(uint32_t x, int r) {
    return (x << r) | (x >> (32 - r));
}

__device__ __forceinline__ uint32_t threefry_bits_part(uint32_t i) {
    uint32_t x0 = 0u;        // i >> 32 for i < 2^32
    uint32_t x1 = i;
    const uint32_t ks0 = 0u, ks1 = 1u, ks2 = 0x1BD11BDAu ^ 0u ^ 1u;
    x0 += ks0; x1 += ks1;
#define TFR(r) { x0 += x1; x1 = rotl32(x1, (r)); x1 ^= x0; }
    TFR(13) TFR(15) TFR(26) TFR(6)
    x0 += ks1; x1 += ks2 + 1u;
    TFR(17) TFR(29) TFR(16) TFR(24)
    x0 += ks2; x1 += ks0 + 2u;
    TFR(13) TFR(15) TFR(26) TFR(6)
    x0 += ks0; x1 += ks1 + 3u;
    TFR(17) TFR(29) TFR(16) TFR(24)
    x0 += ks1; x1 += ks2 + 4u;
    TFR(13) TFR(15) TFR(26) TFR(6)
    x0 += ks2; x1 += ks0 + 5u;
#undef TFR
    return x0 ^ x1;
}

// ---------------- K3: relu + fc2 + log_softmax + gumbel sample, one wave/sample ----
template <int KSP>
__global__ __launch_bounds__(64) void head_kernel(const int* __restrict__ raw,
                                                  const float* __restrict__ hpre,
                                                  const float* __restrict__ b1,
                                                  const float* __restrict__ w2,
                                                  const float* __restrict__ b2,
                                                  float* __restrict__ out) {
    __shared__ __align__(16) float w2l[H_DIM * A_DIM];   // 9216 floats = 36 KB
    __shared__ float red[16][A_DIM];
    __shared__ float logits_lds[A_DIM];

    int s = blockIdx.x;
    int lane = threadIdx.x;
    bool is32 = taskid_is_int32(raw, lane);
    int t = is32 ? raw[s] : raw[2 * s];

    // ---- stage w2[t] into LDS, coalesced: 9216 floats = 36 float4 per lane ----
    const float4* g4 = (const float4*)(w2 + (size_t)t * (H_DIM * A_DIM));
    float4* l4 = (float4*)w2l;
#pragma unroll
    for (int i = 0; i < (H_DIM * A_DIM) / (64 * 4); ++i)   // 36 iters
        l4[i * 64 + lane] = g4[i * 64 + lane];

    // ---- h = relu(sum_k partial_k + b1) (overlaps with staging latency) ----
    float hreg[H_DIM / 64];
#pragma unroll
    for (int k = 0; k < H_DIM / 64; ++k) {
        int h = lane + 64 * k;
        size_t p = (size_t)s * H_DIM + h;
        float v = b1[(size_t)t * H_DIM + h];
#pragma unroll
        for (int q = 0; q < KSP; ++q)
            v += hpre[(size_t)q * ((size_t)B_N * H_DIM) + p];
        hreg[k] = fmaxf(v, 0.f);
    }
    __syncthreads();   // w2l visible (single wave: cheap)

    // ---- per-lane partial logits from LDS ----
    float la[A_DIM];
#pragma unroll
    for (int a = 0; a < A_DIM; ++a) la[a] = 0.f;
#pragma unroll
    for (int k = 0; k < H_DIM / 64; ++k) {
        int h = lane + 64 * k;
        const float2* row = (const float2*)&w2l[h * A_DIM];   // 72 B rows: 8 B aligned
        float hk = hreg[k];
#pragma unroll
        for (int a2 = 0; a2 < A_DIM / 2; ++a2) {
            float2 ww = row[a2];
            la[2 * a2]     = fmaf(hk, ww.x, la[2 * a2]);
            la[2 * a2 + 1] = fmaf(hk, ww.y, la[2 * a2 + 1]);
        }
    }

    // ---- reduce 64 partials: shfl_xor(1,2) -> 16 rows -> LDS -> 18-lane sum ----
#pragma unroll
    for (int a = 0; a < A_DIM; ++a) {
        la[a] += __shfl_xor(la[a], 1);
        la[a] += __shfl_xor(la[a], 2);
    }
    if ((lane & 3) == 0) {
        int g = lane >> 2;
#pragma unroll
        for (int a = 0; a < A_DIM; ++a) red[g][a] = la[a];
    }
    __syncthreads();
    if (lane < A_DIM) {
        float sum = b2[(size_t)t * A_DIM + lane];
#pragma unroll
        for (int g = 0; g < 16; ++g) sum += red[g][lane];
        logits_lds[lane] = sum;
    }
    __syncthreads();

    // ---- tail: identical to the validated round-4 code ----
    float lg = (lane < A_DIM) ? logits_lds[lane] : -INFINITY;

    float z = -INFINITY;
    if (lane < A_DIM) {
        uint32_t bits = threefry_bits_part((uint32_t)(s * A_DIM + lane));
        float f = __uint_as_float(0x3f800000u | (bits >> 9)) - 1.0f;
        float u = fmaxf(f, 1.17549435e-38f);   // jnp.finfo(f32).tiny
        float g = -logf(-logf(u));
        z = lg + g;
    }
    int idx = lane;
#pragma unroll
    for (int o = 1; o < 64; o <<= 1) {
        float oz = __shfl_xor(z, o);
        int   oi = __shfl_xor(idx, o);
        if (oz > z || (oz == z && oi < idx)) { z = oz; idx = oi; }
    }

    float mx = lg;
#pragma unroll
    for (int o = 1; o < 64; o <<= 1) mx = fmaxf(mx, __shfl_xor(mx, o));
    float e = (lane < A_DIM) ? expf(lg - mx) : 0.f;
#pragma unroll
    for (int o = 1; o < 64; o <<= 1) e += __shfl_xor(e, o);
    float lse = mx + logf(e);
    float lp = lg - lse;
    float c = (lane < A_DIM) ? expf(lp) * lp : 0.f;
#pragma unroll
    for (int o = 1; o < 64; o <<= 1) c += __shfl_xor(c, o);

    if (lane == 0) {
        out[s]             = (float)idx;            // action
        out[B_N + s]       = logits_lds[idx] - lse; // log_prob
        out[2 * B_N + s]   = -c;                    // entropy
    }
}

extern "C" void kernel_launch(void* const* d_in, const int* in_sizes, int n_in,
                              void* d_out, int out_size, void* d_ws, size_t ws_size,
                              hipStream_t stream) {
    const float* xs      = (const float*)d_in[0];
    const int*   traw    = (const int*)d_in[1];   // int32 or int64 — detected on device
    const float* w1      = (const float*)d_in[2];
    const float* b1      = (const float*)d_in[3];
    const float* w2      = (const float*)d_in[4];
    const float* b2      = (const float*)d_in[5];
    float* out = (float*)d_out;
    char*  ws  = (char*)d_ws;

    const size_t part_bytes = (size_t)B_N * H_DIM * sizeof(float);  // 2 MB per K-split partial

    // Pick K-split by available workspace (constant per process -> graph-safe).
    int ksp = 4;
    if (ws_size < 4 * part_bytes) ksp = 2;
    if (ws_size < 2 * part_bytes) ksp = 1;

    float* hpre = (float*)ws;

    if (ksp == 4) {
        fc1_kernel<4><<<dim3(T_N, 2, 4), 256, 0, stream>>>(xs, w1, traw, hpre);
        head_kernel<4><<<B_N, 64, 0, stream>>>(traw, hpre, b1, w2, b2, out);
    } else if (ksp == 2) {
        fc1_kernel<2><<<dim3(T_N, 2, 2), 256, 0, stream>>>(xs, w1, traw, hpre);
        head_kernel<2><<<B_N, 64, 0, stream>>>(traw, hpre, b1, w2, b2, out);
    } else {
        fc1_kernel<1><<<dim3(T_N, 2, 1), 256, 0, stream>>>(xs, w1, traw, hpre);
        head_kernel<1><<<B_N, 64, 0, stream>>>(traw, hpre, b1, w2, b2, out);
    }
}